// Round 1
// baseline (438.645 us; speedup 1.0000x reference)
//
#include <hip/hip_runtime.h>
#include <math.h>

#define BB 16
#define MM 2048
#define SS 6
#define EE 128
#define LCC 512
#define VV 32000
#define TWO_E 256

// ---------------------------------------------------------------------------
// Fused embedding-sum + add_lm + 2-layer MLP (MLP_A) over all B*M rows.
// Each block: 32 rows, 256 threads (2 row-groups x 128 cols).
//   x[r][0:128]   = sum_s C_k[story[b,m,s]] (+ dh window)
//   x[r][128:256] = tf_hidden[b]
//   h = lrelu(x @ W1 + b1);  y = h @ W2 + b2  -> out[row][e]
// ---------------------------------------------------------------------------
__global__ __launch_bounds__(256)
void embed_mlp_kernel(const int* __restrict__ story,
                      const int* __restrict__ kb_len,
                      const int* __restrict__ conv_len,
                      const float* __restrict__ dh,   // [B,LC,E]
                      const float* __restrict__ tf,   // [B,E]
                      const float* __restrict__ Ck,   // C + k*V*E
                      const float* __restrict__ W1,   // [256,128]
                      const float* __restrict__ b1,   // [128]
                      const float* __restrict__ W2,   // [128,128]
                      const float* __restrict__ b2,   // [128]
                      float* __restrict__ out)        // [B*M,128]
{
    __shared__ float xs[32][TWO_E];   // 32 KB
    __shared__ float hs[32][EE];      // 16 KB

    const int tid    = threadIdx.x;
    const int rgroup = tid >> 7;      // 0..1
    const int e      = tid & 127;
    const int row0   = blockIdx.x * 32;
    const int b      = row0 >> 11;    // M = 2048, blocks never straddle b
    const int kb     = kb_len[b];
    const int cl     = conv_len[b];
    const float tfv  = tf[b * EE + e];

    // ---- stage x into LDS ----
    for (int rr = 0; rr < 16; ++rr) {
        const int r   = rgroup * 16 + rr;
        const int row = row0 + r;
        const int m   = row & (MM - 1);
        const int* st = story + (size_t)row * SS;
        float acc = 0.f;
        #pragma unroll
        for (int s = 0; s < SS; ++s) {
            acc += Ck[(size_t)st[s] * EE + e];
        }
        const int j = m - kb;
        if (j >= 0 && j < cl) acc += dh[((size_t)b * LCC + j) * EE + e];
        xs[r][e]      = acc;
        xs[r][EE + e] = tfv;
    }
    __syncthreads();

    // ---- stage 1: H = lrelu(X @ W1 + b1). thread -> col e, 16 rows ----
    const int r0 = rgroup * 16;
    float acc[16];
    #pragma unroll
    for (int i = 0; i < 16; ++i) acc[i] = 0.f;

    const float4* xs4 = (const float4*)&xs[0][0];   // row stride 64 float4
    for (int k4 = 0; k4 < TWO_E / 4; ++k4) {
        const float w0 = W1[(k4 * 4 + 0) * EE + e];
        const float w1 = W1[(k4 * 4 + 1) * EE + e];
        const float w2 = W1[(k4 * 4 + 2) * EE + e];
        const float w3 = W1[(k4 * 4 + 3) * EE + e];
        #pragma unroll
        for (int rr = 0; rr < 16; ++rr) {
            const float4 xv = xs4[(r0 + rr) * (TWO_E / 4) + k4];
            acc[rr] += xv.x * w0 + xv.y * w1 + xv.z * w2 + xv.w * w3;
        }
    }
    const float bias1 = b1[e];
    #pragma unroll
    for (int rr = 0; rr < 16; ++rr) {
        const float h = acc[rr] + bias1;
        hs[r0 + rr][e] = (h > 0.f) ? h : 0.1f * h;   // LeakyReLU(0.1)
    }
    __syncthreads();

    // ---- stage 2: Y = H @ W2 + b2 ----
    float acc2[16];
    #pragma unroll
    for (int i = 0; i < 16; ++i) acc2[i] = 0.f;

    const float4* hs4 = (const float4*)&hs[0][0];   // row stride 32 float4
    for (int k4 = 0; k4 < EE / 4; ++k4) {
        const float w0 = W2[(k4 * 4 + 0) * EE + e];
        const float w1 = W2[(k4 * 4 + 1) * EE + e];
        const float w2 = W2[(k4 * 4 + 2) * EE + e];
        const float w3 = W2[(k4 * 4 + 3) * EE + e];
        #pragma unroll
        for (int rr = 0; rr < 16; ++rr) {
            const float4 hv = hs4[(r0 + rr) * (EE / 4) + k4];
            acc2[rr] += hv.x * w0 + hv.y * w1 + hv.z * w2 + hv.w * w3;
        }
    }
    const float bias2 = b2[e];
    #pragma unroll
    for (int rr = 0; rr < 16; ++rr) {
        out[(size_t)(row0 + r0 + rr) * EE + e] = acc2[rr] + bias2;
    }
}

// ---------------------------------------------------------------------------
// logits[b,m] = gp[b,m] * sum_e m_k[b,m,e] * uq[b,e]   (wave per row)
// ---------------------------------------------------------------------------
__global__ __launch_bounds__(256)
void logits_kernel(const float* __restrict__ mk, const float* __restrict__ gp,
                   const float* __restrict__ uq, float* __restrict__ out)
{
    const int row  = blockIdx.x * 4 + (threadIdx.x >> 6);
    const int lane = threadIdx.x & 63;
    const int b    = row >> 11;
    const float* rp  = mk + (size_t)row * EE;
    const float* uqb = uq + b * EE;
    float s = rp[lane] * uqb[lane] + rp[lane + 64] * uqb[lane + 64];
    #pragma unroll
    for (int off = 32; off > 0; off >>= 1) s += __shfl_down(s, off, 64);
    if (lane == 0) out[row] = s * gp[row];
}

// ---------------------------------------------------------------------------
// softmax over M per batch row (stable). block per b, 256 threads, 8 elem/thr
// ---------------------------------------------------------------------------
__global__ __launch_bounds__(256)
void softmax_kernel(const float* __restrict__ logits, float* __restrict__ soft)
{
    __shared__ float red[256];
    const int b   = blockIdx.x;
    const int tid = threadIdx.x;
    const float* lb = logits + (size_t)b * MM;
    float v[8];
    float mx = -1e30f;
    #pragma unroll
    for (int i = 0; i < 8; ++i) { v[i] = lb[i * 256 + tid]; mx = fmaxf(mx, v[i]); }
    red[tid] = mx; __syncthreads();
    for (int s = 128; s > 0; s >>= 1) {
        if (tid < s) red[tid] = fmaxf(red[tid], red[tid + s]);
        __syncthreads();
    }
    mx = red[0]; __syncthreads();
    float sum = 0.f;
    #pragma unroll
    for (int i = 0; i < 8; ++i) { v[i] = expf(v[i] - mx); sum += v[i]; }
    red[tid] = sum; __syncthreads();
    for (int s = 128; s > 0; s >>= 1) {
        if (tid < s) red[tid] += red[tid + s];
        __syncthreads();
    }
    const float inv = 1.f / red[0];
    #pragma unroll
    for (int i = 0; i < 8; ++i) soft[(size_t)b * MM + i * 256 + tid] = v[i] * inv;
}

// ---------------------------------------------------------------------------
// uq[b,e] += sum_m m_{k+1}[b,m,e] * gp[b,m] * soft[b,m]
// grid: B*16 blocks (M chunked by 128), 128 threads = e. fp32 atomics.
// ---------------------------------------------------------------------------
__global__ __launch_bounds__(128)
void update_kernel(const float* __restrict__ mk1, const float* __restrict__ gp,
                   const float* __restrict__ soft, float* __restrict__ uq)
{
    const int bid = blockIdx.x;
    const int b   = bid >> 4;
    const int c   = bid & 15;
    const int e   = threadIdx.x;
    float acc = 0.f;
    for (int mm = 0; mm < MM / 16; ++mm) {
        const int m = c * (MM / 16) + mm;
        const float w = gp[(size_t)b * MM + m] * soft[(size_t)b * MM + m];
        acc += mk1[((size_t)b * MM + m) * EE + e] * w;
    }
    atomicAdd(&uq[b * EE + e], acc);
}

__global__ __launch_bounds__(256)
void init_uq_kernel(const float* __restrict__ query, float* __restrict__ uq)
{
    const int i = blockIdx.x * 256 + threadIdx.x;
    if (i < BB * EE) uq[i] = query[i];
}

// ---------------------------------------------------------------------------
extern "C" void kernel_launch(void* const* d_in, const int* in_sizes, int n_in,
                              void* d_out, int out_size, void* d_ws, size_t ws_size,
                              hipStream_t stream) {
    const int*   story    = (const int*)d_in[0];
    const int*   kb_len   = (const int*)d_in[1];
    const int*   conv_len = (const int*)d_in[2];
    // d_in[3] = hidden (dead code w.r.t. outputs)
    const float* dh       = (const float*)d_in[4];
    const float* tf       = (const float*)d_in[5];
    const float* query    = (const float*)d_in[6];
    const float* gp       = (const float*)d_in[7];
    const float* C        = (const float*)d_in[8];
    const float* wA1      = (const float*)d_in[9];
    const float* bA1      = (const float*)d_in[10];
    const float* wA2      = (const float*)d_in[11];
    const float* bA2      = (const float*)d_in[12];
    // wC1/bC1/wC2/bC2 (13-16), wf/bf (17-18): dead code w.r.t. outputs

    float* ws   = (float*)d_ws;
    const size_t BME = (size_t)BB * MM * EE;   // 4,194,304
    float* m0   = ws;
    float* m1   = m0 + BME;
    float* m2   = m1 + BME;
    float* lbuf = m2 + BME;
    float* sbuf = lbuf + (size_t)BB * MM;
    float* uq   = sbuf + (size_t)BB * MM;

    float* out_soft   = (float*)d_out;            // prob_soft   [B,M]
    float* out_logits = out_soft + (size_t)BB * MM; // prob_logits [B,M]

    const size_t VE = (size_t)VV * EE;

    // m_k = MLP_A(concat(embed_k, tf)), k = 0,1,2
    embed_mlp_kernel<<<BB * MM / 32, 256, 0, stream>>>(story, kb_len, conv_len, dh, tf,
                                                       C + 0 * VE, wA1, bA1, wA2, bA2, m0);
    embed_mlp_kernel<<<BB * MM / 32, 256, 0, stream>>>(story, kb_len, conv_len, dh, tf,
                                                       C + 1 * VE, wA1, bA1, wA2, bA2, m1);
    embed_mlp_kernel<<<BB * MM / 32, 256, 0, stream>>>(story, kb_len, conv_len, dh, tf,
                                                       C + 2 * VE, wA1, bA1, wA2, bA2, m2);

    init_uq_kernel<<<(BB * EE + 255) / 256, 256, 0, stream>>>(query, uq);

    // hop 0
    logits_kernel<<<BB * MM / 4, 256, 0, stream>>>(m0, gp, uq, lbuf);
    softmax_kernel<<<BB, 256, 0, stream>>>(lbuf, sbuf);
    update_kernel<<<BB * 16, 128, 0, stream>>>(m1, gp, sbuf, uq);
    // hop 1
    logits_kernel<<<BB * MM / 4, 256, 0, stream>>>(m1, gp, uq, lbuf);
    softmax_kernel<<<BB, 256, 0, stream>>>(lbuf, sbuf);
    update_kernel<<<BB * 16, 128, 0, stream>>>(m2, gp, sbuf, uq);
    // hop 2 (final): logits -> d_out[B*M:], softmax -> d_out[0:B*M]
    logits_kernel<<<BB * MM / 4, 256, 0, stream>>>(m2, gp, uq, out_logits);
    softmax_kernel<<<BB, 256, 0, stream>>>(out_logits, out_soft);
}

// Round 2
// 395.520 us; speedup vs baseline: 1.1090x; 1.1090x over previous
//
#include <hip/hip_runtime.h>
#include <math.h>

#define BB 16
#define MM 2048
#define SS 6
#define EE 128
#define LCC 512
#define VV 32000

typedef __attribute__((ext_vector_type(8))) __bf16 bf16x8;
typedef __attribute__((ext_vector_type(4))) float f32x4;

#define XS_STRIDE 264   // 256 + 8 bf16 pad: row stride 528 B == 4 banks mod 32 -> 2-way (free)
#define HS_STRIDE 136   // 128 + 8 bf16 pad: row stride 272 B, 16B-aligned for ds_read_b128

// ---------------------------------------------------------------------------
// prep: W1 [256x128] fp32 -> w1t bf16 [n=128][k=256]; W2 [128x128] -> w2t [128][128]
// ---------------------------------------------------------------------------
__global__ __launch_bounds__(256)
void prep_weights(const float* __restrict__ W1, const float* __restrict__ W2,
                  __bf16* __restrict__ w1t, __bf16* __restrict__ w2t)
{
    const int i = blockIdx.x * 256 + threadIdx.x;
    if (i < 128 * 256) {
        const int n = i >> 8, k = i & 255;
        w1t[i] = (__bf16)W1[k * EE + n];
    } else if (i < 128 * 256 + 128 * 128) {
        const int j = i - 128 * 256;
        const int n = j >> 7, k = j & 127;
        w2t[j] = (__bf16)W2[k * EE + n];
    }
}

// ---------------------------------------------------------------------------
// Fused (3 hops in one grid): embed gather-sum + add_lm -> bf16 X in LDS ->
// GEMM1 (MFMA, K=256) -> lrelu -> H in LDS -> GEMM2 (K=128) -> m_k bf16.
// Block: 64 rows x 128 cols, 256 threads = 4 waves; wave w owns cols w*32..+31.
// ---------------------------------------------------------------------------
__global__ __launch_bounds__(256)
void embed_mlp_mfma(const int* __restrict__ story,
                    const int* __restrict__ kb_len,
                    const int* __restrict__ conv_len,
                    const float* __restrict__ dh,
                    const float* __restrict__ tf,
                    const float* __restrict__ C,
                    const __bf16* __restrict__ w1t, const float* __restrict__ b1,
                    const __bf16* __restrict__ w2t, const float* __restrict__ b2,
                    __bf16* __restrict__ mout)
{
    __shared__ __bf16 Xs[64 * XS_STRIDE];   // 33,792 B
    __shared__ __bf16 Hs[64 * HS_STRIDE];   // 17,408 B
    __shared__ int    sidx[64 * SS];

    const int bid  = blockIdx.x;
    const int hop  = bid >> 9;              // 512 blocks per hop
    const int row0 = (bid & 511) * 64;      // global row in [0, 32768)
    const int b    = row0 >> 11;
    const int tid  = threadIdx.x;

    const float* Ck  = C + (size_t)hop * VV * EE;
    __bf16*      out = mout + (size_t)hop * 32768 * EE;

    // ---- stage story indices ----
    for (int i = tid; i < 64 * SS; i += 256) sidx[i] = story[(size_t)row0 * SS + i];
    __syncthreads();

    // ---- stage X (bf16) ----
    {
        const int e  = tid & 127;
        const int rg = tid >> 7;
        const int kb = kb_len[b];
        const int cl = conv_len[b];
        const __bf16 tfv = (__bf16)tf[b * EE + e];
        for (int rr = 0; rr < 32; ++rr) {
            const int r = rg * 32 + rr;
            const int m = (row0 + r) & (MM - 1);
            float acc = 0.f;
            #pragma unroll
            for (int s = 0; s < SS; ++s)
                acc += Ck[(size_t)sidx[r * SS + s] * EE + e];
            const int j = m - kb;
            if (j >= 0 && j < cl) acc += dh[((size_t)b * LCC + j) * EE + e];
            Xs[r * XS_STRIDE + e]      = (__bf16)acc;
            Xs[r * XS_STRIDE + EE + e] = tfv;
        }
    }
    __syncthreads();

    const int w       = tid >> 6;
    const int lane    = tid & 63;
    const int lr      = lane & 15;          // m (A) / n (B) index in tile
    const int lk      = lane >> 4;          // k-chunk 0..3
    const int colbase = w * 32;

    // ---- GEMM1: H = lrelu(X @ W1 + b1) ----
    f32x4 acc1[4][2];
    #pragma unroll
    for (int i = 0; i < 4; ++i)
        #pragma unroll
        for (int j = 0; j < 2; ++j) acc1[i][j] = (f32x4){0.f, 0.f, 0.f, 0.f};

    for (int ks = 0; ks < 8; ++ks) {
        bf16x8 a[4], bf[2];
        #pragma unroll
        for (int mt = 0; mt < 4; ++mt)
            a[mt] = *(const bf16x8*)&Xs[(mt * 16 + lr) * XS_STRIDE + ks * 32 + lk * 8];
        #pragma unroll
        for (int nt = 0; nt < 2; ++nt)
            bf[nt] = *(const bf16x8*)&w1t[(size_t)(colbase + nt * 16 + lr) * 256 + ks * 32 + lk * 8];
        #pragma unroll
        for (int mt = 0; mt < 4; ++mt)
            #pragma unroll
            for (int nt = 0; nt < 2; ++nt)
                acc1[mt][nt] = __builtin_amdgcn_mfma_f32_16x16x32_bf16(a[mt], bf[nt], acc1[mt][nt], 0, 0, 0);
    }
    {
        const float b1v[2] = { b1[colbase + lr], b1[colbase + 16 + lr] };
        #pragma unroll
        for (int mt = 0; mt < 4; ++mt)
            #pragma unroll
            for (int nt = 0; nt < 2; ++nt)
                #pragma unroll
                for (int reg = 0; reg < 4; ++reg) {
                    float h = acc1[mt][nt][reg] + b1v[nt];
                    h = (h > 0.f) ? h : 0.1f * h;   // LeakyReLU(0.1)
                    Hs[(mt * 16 + lk * 4 + reg) * HS_STRIDE + colbase + nt * 16 + lr] = (__bf16)h;
                }
    }
    __syncthreads();

    // ---- GEMM2: Y = H @ W2 + b2 ----
    f32x4 acc2[4][2];
    #pragma unroll
    for (int i = 0; i < 4; ++i)
        #pragma unroll
        for (int j = 0; j < 2; ++j) acc2[i][j] = (f32x4){0.f, 0.f, 0.f, 0.f};

    for (int ks = 0; ks < 4; ++ks) {
        bf16x8 a[4], bf[2];
        #pragma unroll
        for (int mt = 0; mt < 4; ++mt)
            a[mt] = *(const bf16x8*)&Hs[(mt * 16 + lr) * HS_STRIDE + ks * 32 + lk * 8];
        #pragma unroll
        for (int nt = 0; nt < 2; ++nt)
            bf[nt] = *(const bf16x8*)&w2t[(size_t)(colbase + nt * 16 + lr) * 128 + ks * 32 + lk * 8];
        #pragma unroll
        for (int mt = 0; mt < 4; ++mt)
            #pragma unroll
            for (int nt = 0; nt < 2; ++nt)
                acc2[mt][nt] = __builtin_amdgcn_mfma_f32_16x16x32_bf16(a[mt], bf[nt], acc2[mt][nt], 0, 0, 0);
    }
    {
        const float b2v[2] = { b2[colbase + lr], b2[colbase + 16 + lr] };
        #pragma unroll
        for (int mt = 0; mt < 4; ++mt)
            #pragma unroll
            for (int nt = 0; nt < 2; ++nt)
                #pragma unroll
                for (int reg = 0; reg < 4; ++reg) {
                    const int rg_ = row0 + mt * 16 + lk * 4 + reg;
                    out[(size_t)rg_ * EE + colbase + nt * 16 + lr] =
                        (__bf16)(acc2[mt][nt][reg] + b2v[nt]);
                }
    }
}

// ---------------------------------------------------------------------------
// One hop, block per batch row b (16 blocks x 1024 threads = 16 waves):
//   if do_update: uq = uq_in + sum_m gp*soft_prev * m_k[b,m,:]
//   logits[m] = gp[b,m] * dot(m_k[b,m,:], uq);  softmax -> soft_out
// ---------------------------------------------------------------------------
__global__ __launch_bounds__(1024)
void hop_kernel(const __bf16* __restrict__ mk, const float* __restrict__ gp,
                const float* __restrict__ uq_in, const float* __restrict__ soft_prev,
                float* __restrict__ uq_out, float* __restrict__ soft_out,
                float* __restrict__ logits_out, const int do_update)
{
    __shared__ float uqs[128];
    __shared__ float wbuf[2048];
    __shared__ float lbuf[2048];
    __shared__ float partial[16][128];
    __shared__ float red[1024];

    const int b    = blockIdx.x;
    const int tid  = threadIdx.x;
    const int w    = tid >> 6;
    const int lane = tid & 63;

    if (tid < 128) uqs[tid] = uq_in[b * 128 + tid];

    if (do_update) {
        for (int i = tid; i < 2048; i += 1024)
            wbuf[i] = gp[b * 2048 + i] * soft_prev[b * 2048 + i];
        __syncthreads();
        float p0 = 0.f, p1 = 0.f;
        const size_t base = ((size_t)b * 2048 + w * 128) * 128;
        for (int r = 0; r < 128; ++r) {
            const float wgt = wbuf[w * 128 + r];
            p0 += wgt * (float)mk[base + r * 128 + lane];
            p1 += wgt * (float)mk[base + r * 128 + 64 + lane];
        }
        partial[w][lane]      = p0;
        partial[w][lane + 64] = p1;
        __syncthreads();
        if (tid < 128) {
            float s = uqs[tid];
            #pragma unroll
            for (int ww = 0; ww < 16; ++ww) s += partial[ww][tid];
            uqs[tid] = s;
            if (uq_out) uq_out[b * 128 + tid] = s;
        }
    }
    __syncthreads();

    // ---- logits: wave w handles rows w*128 .. w*128+127 ----
    {
        const float u0 = uqs[lane], u1 = uqs[lane + 64];
        const size_t base = ((size_t)b * 2048 + w * 128) * 128;
        for (int r = 0; r < 128; ++r) {
            float s = (float)mk[base + r * 128 + lane] * u0
                    + (float)mk[base + r * 128 + 64 + lane] * u1;
            #pragma unroll
            for (int off = 32; off > 0; off >>= 1) s += __shfl_down(s, off, 64);
            if (lane == 0) lbuf[w * 128 + r] = s * gp[b * 2048 + w * 128 + r];
        }
    }
    __syncthreads();

    // ---- softmax over 2048 ----
    const float v0 = lbuf[tid], v1 = lbuf[tid + 1024];
    red[tid] = fmaxf(v0, v1);
    __syncthreads();
    for (int s = 512; s > 0; s >>= 1) {
        if (tid < s) red[tid] = fmaxf(red[tid], red[tid + s]);
        __syncthreads();
    }
    const float mx = red[0];
    __syncthreads();
    const float e0 = expf(v0 - mx), e1 = expf(v1 - mx);
    red[tid] = e0 + e1;
    __syncthreads();
    for (int s = 512; s > 0; s >>= 1) {
        if (tid < s) red[tid] += red[tid + s];
        __syncthreads();
    }
    const float inv = 1.f / red[0];
    soft_out[b * 2048 + tid]        = e0 * inv;
    soft_out[b * 2048 + tid + 1024] = e1 * inv;
    if (logits_out) {
        logits_out[b * 2048 + tid]        = v0;
        logits_out[b * 2048 + tid + 1024] = v1;
    }
}

// ---------------------------------------------------------------------------
extern "C" void kernel_launch(void* const* d_in, const int* in_sizes, int n_in,
                              void* d_out, int out_size, void* d_ws, size_t ws_size,
                              hipStream_t stream) {
    const int*   story    = (const int*)d_in[0];
    const int*   kb_len   = (const int*)d_in[1];
    const int*   conv_len = (const int*)d_in[2];
    // d_in[3] = hidden (dead w.r.t. outputs)
    const float* dh       = (const float*)d_in[4];
    const float* tf       = (const float*)d_in[5];
    const float* query    = (const float*)d_in[6];
    const float* gp       = (const float*)d_in[7];
    const float* C        = (const float*)d_in[8];
    const float* wA1      = (const float*)d_in[9];
    const float* bA1      = (const float*)d_in[10];
    const float* wA2      = (const float*)d_in[11];
    const float* bA2      = (const float*)d_in[12];
    // wC1/bC1/wC2/bC2, wf/bf: dead w.r.t. outputs

    char* ws = (char*)d_ws;
    const size_t M_ELEMS = (size_t)32768 * 128;      // per hop
    __bf16* m   = (__bf16*)ws;                       // 3 * 8 MB bf16
    size_t off  = 3 * M_ELEMS * sizeof(__bf16);
    __bf16* w1t = (__bf16*)(ws + off); off += 128 * 256 * sizeof(__bf16);
    __bf16* w2t = (__bf16*)(ws + off); off += 128 * 128 * sizeof(__bf16);
    float* soft0 = (float*)(ws + off); off += (size_t)BB * MM * sizeof(float);
    float* soft1 = (float*)(ws + off); off += (size_t)BB * MM * sizeof(float);
    float* uq1   = (float*)(ws + off); off += (size_t)BB * EE * sizeof(float);

    float* out_soft   = (float*)d_out;               // prob_soft   [B,M]
    float* out_logits = out_soft + (size_t)BB * MM;  // prob_logits [B,M]

    prep_weights<<<192, 256, 0, stream>>>(wA1, wA2, w1t, w2t);
    embed_mlp_mfma<<<1536, 256, 0, stream>>>(story, kb_len, conv_len, dh, tf, C,
                                             w1t, bA1, w2t, bA2, m);
    // hop 0: logits(m0, query) -> soft0
    hop_kernel<<<BB, 1024, 0, stream>>>(m, gp, query, nullptr, nullptr,
                                        soft0, nullptr, 0);
    // hop 1: uq1 = query + upd(m1, soft0); logits(m1, uq1) -> soft1
    hop_kernel<<<BB, 1024, 0, stream>>>(m + M_ELEMS, gp, query, soft0, uq1,
                                        soft1, nullptr, 1);
    // hop 2: uq2 = uq1 + upd(m2, soft1); logits(m2, uq2) -> outputs
    hop_kernel<<<BB, 1024, 0, stream>>>(m + 2 * M_ELEMS, gp, uq1, soft1, nullptr,
                                        out_soft, out_logits, 1);
}

// Round 3
// 206.940 us; speedup vs baseline: 2.1197x; 1.9113x over previous
//
#include <hip/hip_runtime.h>
#include <math.h>

#define BB 16
#define MM 2048
#define SS 6
#define EE 128
#define LCC 512
#define VV 32000

typedef __attribute__((ext_vector_type(8))) __bf16 bf16x8;
typedef __attribute__((ext_vector_type(4))) __bf16 bf16x4;
typedef __attribute__((ext_vector_type(4))) float f32x4;

#define XS_STRIDE 264   // 256+8 bf16 pad: 528 B/row; 528/16=33 (odd) -> rows 0..7 cover all banks, 2-way (free)
#define HS_STRIDE 136   // 128+8 bf16 pad: 272 B/row; 272/16=17 (odd) -> same

static __device__ inline unsigned short bfbits(float x) {
    __bf16 h = (__bf16)x;
    return __builtin_bit_cast(unsigned short, h);
}

// ---------------------------------------------------------------------------
// prep: W1 [256x128] fp32 -> w1t bf16 [n=128][k=256]; W2 [128x128] -> w2t [128][128]
// ---------------------------------------------------------------------------
__global__ __launch_bounds__(256)
void prep_weights(const float* __restrict__ W1, const float* __restrict__ W2,
                  __bf16* __restrict__ w1t, __bf16* __restrict__ w2t)
{
    const int i = blockIdx.x * 256 + threadIdx.x;
    if (i < 128 * 256) {
        const int n = i >> 8, k = i & 255;
        w1t[i] = (__bf16)W1[k * EE + n];
    } else if (i < 128 * 256 + 128 * 128) {
        const int j = i - 128 * 256;
        const int n = j >> 7, k = j & 127;
        w2t[j] = (__bf16)W2[k * EE + n];
    }
}

// ---------------------------------------------------------------------------
// Fused (3 hops in one grid, 3072 blocks x 32 rows): gather-sum + add_lm ->
// bf16 X in LDS -> MFMA GEMM1 (K=256) -> lrelu -> H -> GEMM2 (K=128) -> m_k.
// 256 threads = 4 waves. LDS ~26.4 KB -> 6 blocks/CU.
// ---------------------------------------------------------------------------
__global__ __launch_bounds__(256)
void embed_mlp_mfma(const int* __restrict__ story,
                    const int* __restrict__ kb_len,
                    const int* __restrict__ conv_len,
                    const float* __restrict__ dh,
                    const float* __restrict__ tf,
                    const float* __restrict__ C,
                    const __bf16* __restrict__ w1t, const float* __restrict__ b1,
                    const __bf16* __restrict__ w2t, const float* __restrict__ b2,
                    __bf16* __restrict__ mout)
{
    __shared__ __bf16 Xs[32 * XS_STRIDE];   // 16,896 B
    __shared__ __bf16 Hs[32 * HS_STRIDE];   //  8,704 B
    __shared__ int    sidx[32 * SS];

    const int bid  = blockIdx.x;
    const int hop  = bid >> 10;             // 1024 blocks per hop
    const int row0 = (bid & 1023) * 32;     // global row in [0, 32768)
    const int b    = row0 >> 11;
    const int tid  = threadIdx.x;

    const float* Ck  = C + (size_t)hop * VV * EE;
    __bf16*      out = mout + (size_t)hop * 32768 * EE;

    for (int i = tid; i < 32 * SS; i += 256) sidx[i] = story[(size_t)row0 * SS + i];

    const int kb   = kb_len[b];
    const int cl   = conv_len[b];
    const int trow = tid >> 5;              // 0..7
    const int e4   = (tid & 31) * 4;        // col group (4 floats / 16 B)
    const float4 tf4 = *(const float4*)&tf[b * EE + e4];
    ushort4 tfp;
    tfp.x = bfbits(tf4.x); tfp.y = bfbits(tf4.y); tfp.z = bfbits(tf4.z); tfp.w = bfbits(tf4.w);
    __syncthreads();

    // ---- gather-stage X (float4 reads, packed bf16x4 LDS stores) ----
    for (int chunk = 0; chunk < 4; ++chunk) {
        const int r = chunk * 8 + trow;
        const int m = (row0 + r) & (MM - 1);
        const int* si = &sidx[r * SS];
        float4 acc = {0.f, 0.f, 0.f, 0.f};
        #pragma unroll
        for (int s = 0; s < SS; ++s) {
            const float4 v = *(const float4*)&Ck[(size_t)si[s] * EE + e4];
            acc.x += v.x; acc.y += v.y; acc.z += v.z; acc.w += v.w;
        }
        const int j = m - kb;
        if (j >= 0 && j < cl) {
            const float4 dv = *(const float4*)&dh[((size_t)b * LCC + j) * EE + e4];
            acc.x += dv.x; acc.y += dv.y; acc.z += dv.z; acc.w += dv.w;
        }
        ushort4 pk;
        pk.x = bfbits(acc.x); pk.y = bfbits(acc.y); pk.z = bfbits(acc.z); pk.w = bfbits(acc.w);
        *(ushort4*)&Xs[r * XS_STRIDE + e4]      = pk;
        *(ushort4*)&Xs[r * XS_STRIDE + EE + e4] = tfp;
    }
    __syncthreads();

    const int w       = tid >> 6;
    const int lane    = tid & 63;
    const int lr      = lane & 15;
    const int lk      = lane >> 4;
    const int colbase = w * 32;

    // ---- GEMM1: H = lrelu(X @ W1 + b1) ----
    f32x4 acc1[2][2];
    #pragma unroll
    for (int i = 0; i < 2; ++i)
        #pragma unroll
        for (int j = 0; j < 2; ++j) acc1[i][j] = (f32x4){0.f, 0.f, 0.f, 0.f};

    for (int ks = 0; ks < 8; ++ks) {
        bf16x8 a[2], bw[2];
        #pragma unroll
        for (int mt = 0; mt < 2; ++mt)
            a[mt] = *(const bf16x8*)&Xs[(mt * 16 + lr) * XS_STRIDE + ks * 32 + lk * 8];
        #pragma unroll
        for (int nt = 0; nt < 2; ++nt)
            bw[nt] = *(const bf16x8*)&w1t[(size_t)(colbase + nt * 16 + lr) * 256 + ks * 32 + lk * 8];
        #pragma unroll
        for (int mt = 0; mt < 2; ++mt)
            #pragma unroll
            for (int nt = 0; nt < 2; ++nt)
                acc1[mt][nt] = __builtin_amdgcn_mfma_f32_16x16x32_bf16(a[mt], bw[nt], acc1[mt][nt], 0, 0, 0);
    }
    {
        const float b1v[2] = { b1[colbase + lr], b1[colbase + 16 + lr] };
        #pragma unroll
        for (int mt = 0; mt < 2; ++mt)
            #pragma unroll
            for (int nt = 0; nt < 2; ++nt)
                #pragma unroll
                for (int reg = 0; reg < 4; ++reg) {
                    float h = acc1[mt][nt][reg] + b1v[nt];
                    h = (h > 0.f) ? h : 0.1f * h;
                    Hs[(mt * 16 + lk * 4 + reg) * HS_STRIDE + colbase + nt * 16 + lr] = (__bf16)h;
                }
    }
    __syncthreads();

    // ---- GEMM2: Y = H @ W2 + b2 ----
    f32x4 acc2[2][2];
    #pragma unroll
    for (int i = 0; i < 2; ++i)
        #pragma unroll
        for (int j = 0; j < 2; ++j) acc2[i][j] = (f32x4){0.f, 0.f, 0.f, 0.f};

    for (int ks = 0; ks < 4; ++ks) {
        bf16x8 a[2], bw[2];
        #pragma unroll
        for (int mt = 0; mt < 2; ++mt)
            a[mt] = *(const bf16x8*)&Hs[(mt * 16 + lr) * HS_STRIDE + ks * 32 + lk * 8];
        #pragma unroll
        for (int nt = 0; nt < 2; ++nt)
            bw[nt] = *(const bf16x8*)&w2t[(size_t)(colbase + nt * 16 + lr) * 128 + ks * 32 + lk * 8];
        #pragma unroll
        for (int mt = 0; mt < 2; ++mt)
            #pragma unroll
            for (int nt = 0; nt < 2; ++nt)
                acc2[mt][nt] = __builtin_amdgcn_mfma_f32_16x16x32_bf16(a[mt], bw[nt], acc2[mt][nt], 0, 0, 0);
    }
    {
        const float b2v[2] = { b2[colbase + lr], b2[colbase + 16 + lr] };
        #pragma unroll
        for (int mt = 0; mt < 2; ++mt)
            #pragma unroll
            for (int nt = 0; nt < 2; ++nt)
                #pragma unroll
                for (int reg = 0; reg < 4; ++reg) {
                    const int rg_ = row0 + mt * 16 + lk * 4 + reg;
                    out[(size_t)rg_ * EE + colbase + nt * 16 + lr] =
                        (__bf16)(acc2[mt][nt][reg] + b2v[nt]);
                }
    }
}

// ---------------------------------------------------------------------------
// logits[row] = gp[row] * dot(mk[row,:], uq[b]).  512 blocks x 64 rows.
// 16 lanes per row, bf16x8 loads (16 B/lane), xor-shuffle reduce.
// ---------------------------------------------------------------------------
__global__ __launch_bounds__(256)
void logits_kernel(const __bf16* __restrict__ mk, const float* __restrict__ gp,
                   const float* __restrict__ uq, float* __restrict__ out)
{
    __shared__ float uqs[128];
    const int row0 = blockIdx.x * 64;
    const int b    = row0 >> 11;
    const int tid  = threadIdx.x;
    if (tid < 128) uqs[tid] = uq[b * EE + tid];
    __syncthreads();
    const int w = tid >> 6, lane = tid & 63;
    const int g = lane >> 4, l16 = lane & 15;
    float u[8];
    #pragma unroll
    for (int j = 0; j < 8; ++j) u[j] = uqs[l16 * 8 + j];
    #pragma unroll
    for (int it = 0; it < 4; ++it) {
        const int row = row0 + it * 16 + w * 4 + g;
        const bf16x8 v = *(const bf16x8*)&mk[(size_t)row * EE + l16 * 8];
        float p = 0.f;
        #pragma unroll
        for (int j = 0; j < 8; ++j) p += (float)v[j] * u[j];
        p += __shfl_xor(p, 1, 64);
        p += __shfl_xor(p, 2, 64);
        p += __shfl_xor(p, 4, 64);
        p += __shfl_xor(p, 8, 64);
        if (l16 == 0) out[row] = p * gp[row];
    }
}

// ---------------------------------------------------------------------------
// softmax over M=2048 per b (16 blocks x 256). Optionally emits w=gp*soft,
// copies uq_src -> uq_dst (init before atomic update), and/or writes soft.
// ---------------------------------------------------------------------------
__global__ __launch_bounds__(256)
void softmax_kernel(const float* __restrict__ logits, const float* __restrict__ gp,
                    float* __restrict__ wq_out, const float* __restrict__ uq_src,
                    float* __restrict__ uq_dst, float* __restrict__ soft_out)
{
    __shared__ float redm[4];
    __shared__ float reds[4];
    const int b = blockIdx.x, tid = threadIdx.x;
    const int lane = tid & 63, w = tid >> 6;
    const float* lb = logits + (size_t)b * MM;
    float v[8];
    float mx = -1e30f;
    #pragma unroll
    for (int i = 0; i < 8; ++i) { v[i] = lb[i * 256 + tid]; mx = fmaxf(mx, v[i]); }
    #pragma unroll
    for (int off = 32; off > 0; off >>= 1) mx = fmaxf(mx, __shfl_xor(mx, off, 64));
    if (lane == 0) redm[w] = mx;
    __syncthreads();
    mx = fmaxf(fmaxf(redm[0], redm[1]), fmaxf(redm[2], redm[3]));
    float sum = 0.f;
    #pragma unroll
    for (int i = 0; i < 8; ++i) { v[i] = __expf(v[i] - mx); sum += v[i]; }
    #pragma unroll
    for (int off = 32; off > 0; off >>= 1) sum += __shfl_xor(sum, off, 64);
    if (lane == 0) reds[w] = sum;
    __syncthreads();
    const float inv = 1.f / (reds[0] + reds[1] + reds[2] + reds[3]);
    #pragma unroll
    for (int i = 0; i < 8; ++i) {
        const float s = v[i] * inv;
        const size_t idx = (size_t)b * MM + i * 256 + tid;
        if (soft_out) soft_out[idx] = s;
        if (wq_out)   wq_out[idx]   = s * gp[idx];
    }
    if (uq_dst && tid < 128) uq_dst[b * EE + tid] = uq_src[b * EE + tid];
}

// ---------------------------------------------------------------------------
// uq[b,:] += sum_m wq[b,m] * mk[b,m,:].  512 blocks x 64 rows, LDS reduce,
// 128 fp32 atomics per block.
// ---------------------------------------------------------------------------
__global__ __launch_bounds__(256)
void update_kernel(const __bf16* __restrict__ mk, const float* __restrict__ wq,
                   float* __restrict__ uq)
{
    __shared__ float part[8][128];
    const int b    = blockIdx.x >> 5;
    const int row0 = b * MM + (blockIdx.x & 31) * 64;
    const int tid  = threadIdx.x;
    const int rs   = tid >> 5;        // 0..7
    const int e4   = (tid & 31) * 4;
    float4 acc = {0.f, 0.f, 0.f, 0.f};
    #pragma unroll
    for (int i = 0; i < 8; ++i) {
        const int row = row0 + i * 8 + rs;
        const float wgt = wq[row];
        const bf16x4 vv = *(const bf16x4*)&mk[(size_t)row * EE + e4];
        acc.x += wgt * (float)vv[0];
        acc.y += wgt * (float)vv[1];
        acc.z += wgt * (float)vv[2];
        acc.w += wgt * (float)vv[3];
    }
    *(float4*)&part[rs][e4] = acc;
    __syncthreads();
    if (tid < 128) {
        float s = 0.f;
        #pragma unroll
        for (int i = 0; i < 8; ++i) s += part[i][tid];
        atomicAdd(&uq[b * EE + tid], s);
    }
}

// ---------------------------------------------------------------------------
extern "C" void kernel_launch(void* const* d_in, const int* in_sizes, int n_in,
                              void* d_out, int out_size, void* d_ws, size_t ws_size,
                              hipStream_t stream) {
    const int*   story    = (const int*)d_in[0];
    const int*   kb_len   = (const int*)d_in[1];
    const int*   conv_len = (const int*)d_in[2];
    // d_in[3] = hidden (dead w.r.t. outputs)
    const float* dh       = (const float*)d_in[4];
    const float* tf       = (const float*)d_in[5];
    const float* query    = (const float*)d_in[6];
    const float* gp       = (const float*)d_in[7];
    const float* C        = (const float*)d_in[8];
    const float* wA1      = (const float*)d_in[9];
    const float* bA1      = (const float*)d_in[10];
    const float* wA2      = (const float*)d_in[11];
    const float* bA2      = (const float*)d_in[12];
    // wC1/bC1/wC2/bC2, wf/bf: dead w.r.t. outputs

    char* ws = (char*)d_ws;
    const size_t M_ELEMS = (size_t)32768 * 128;      // per hop
    __bf16* m   = (__bf16*)ws;
    size_t off  = 3 * M_ELEMS * sizeof(__bf16);
    __bf16* w1t = (__bf16*)(ws + off); off += 128 * 256 * sizeof(__bf16);
    __bf16* w2t = (__bf16*)(ws + off); off += 128 * 128 * sizeof(__bf16);
    float* lbuf = (float*)(ws + off);  off += (size_t)BB * MM * sizeof(float);
    float* wbuf = (float*)(ws + off);  off += (size_t)BB * MM * sizeof(float);
    float* uq1  = (float*)(ws + off);  off += (size_t)BB * EE * sizeof(float);
    float* uq2  = (float*)(ws + off);  off += (size_t)BB * EE * sizeof(float);

    float* out_soft   = (float*)d_out;               // prob_soft   [B,M]
    float* out_logits = out_soft + (size_t)BB * MM;  // prob_logits [B,M]

    prep_weights<<<192, 256, 0, stream>>>(wA1, wA2, w1t, w2t);
    embed_mlp_mfma<<<3072, 256, 0, stream>>>(story, kb_len, conv_len, dh, tf, C,
                                             w1t, bA1, w2t, bA2, m);
    // hop 0
    logits_kernel<<<512, 256, 0, stream>>>(m, gp, query, lbuf);
    softmax_kernel<<<BB, 256, 0, stream>>>(lbuf, gp, wbuf, query, uq1, nullptr);
    // hop 1
    update_kernel<<<512, 256, 0, stream>>>(m + M_ELEMS, wbuf, uq1);
    logits_kernel<<<512, 256, 0, stream>>>(m + M_ELEMS, gp, uq1, lbuf);
    softmax_kernel<<<BB, 256, 0, stream>>>(lbuf, gp, wbuf, uq1, uq2, nullptr);
    // hop 2
    update_kernel<<<512, 256, 0, stream>>>(m + 2 * M_ELEMS, wbuf, uq2);
    logits_kernel<<<512, 256, 0, stream>>>(m + 2 * M_ELEMS, gp, uq2, out_logits);
    softmax_kernel<<<BB, 256, 0, stream>>>(out_logits, gp, nullptr, nullptr, nullptr, out_soft);
}

// Round 4
// 195.084 us; speedup vs baseline: 2.2485x; 1.0608x over previous
//
#include <hip/hip_runtime.h>
#include <math.h>

#define BB 16
#define MM 2048
#define SS 6
#define EE 128
#define LCC 512
#define VV 32000

typedef __attribute__((ext_vector_type(8))) __bf16 bf16x8;
typedef __attribute__((ext_vector_type(4))) float f32x4;

#define XS_STRIDE 264   // 256+8 bf16 pad
#define HS_STRIDE 136   // 128+8 bf16 pad

// ---------------------------------------------------------------------------
// megaprep: fp32->bf16 of C[0..3), dh, tf; weight transpose-convert;
// uqA = query, uqB = 0.  All streaming, one dispatch.
// ---------------------------------------------------------------------------
static __device__ inline void cvt8(const float* __restrict__ src, __bf16* __restrict__ dst) {
    const float4 a = *(const float4*)src;
    const float4 b = *(const float4*)(src + 4);
    bf16x8 o;
    o[0] = (__bf16)a.x; o[1] = (__bf16)a.y; o[2] = (__bf16)a.z; o[3] = (__bf16)a.w;
    o[4] = (__bf16)b.x; o[5] = (__bf16)b.y; o[6] = (__bf16)b.z; o[7] = (__bf16)b.w;
    *(bf16x8*)dst = o;
}

#define N_C8  (3 * VV * EE / 8)        // 1,536,000
#define N_D8  (BB * LCC * EE / 8)      // 131,072
#define N_T8  (BB * EE / 8)            // 256
#define N_W1  (256 * 128)              // 32,768
#define N_W2  (128 * 128)              // 16,384
#define N_UQ  (BB * EE)                // 2,048
#define N_PREP (N_C8 + N_D8 + N_T8 + N_W1 + N_W2 + N_UQ)   // 1,718,528

__global__ __launch_bounds__(256)
void megaprep(const float* __restrict__ C, const float* __restrict__ dh,
              const float* __restrict__ tf, const float* __restrict__ W1,
              const float* __restrict__ W2, const float* __restrict__ query,
              __bf16* __restrict__ Cb, __bf16* __restrict__ dhb,
              __bf16* __restrict__ tfb, __bf16* __restrict__ w1t,
              __bf16* __restrict__ w2t, float* __restrict__ uqA,
              float* __restrict__ uqB)
{
    int i = blockIdx.x * 256 + threadIdx.x;
    if (i < N_C8) { cvt8(C + (size_t)i * 8, Cb + (size_t)i * 8); return; }
    i -= N_C8;
    if (i < N_D8) { cvt8(dh + (size_t)i * 8, dhb + (size_t)i * 8); return; }
    i -= N_D8;
    if (i < N_T8) { cvt8(tf + i * 8, tfb + i * 8); return; }
    i -= N_T8;
    if (i < N_W1) { const int n = i >> 8, k = i & 255; w1t[i] = (__bf16)W1[k * EE + n]; return; }
    i -= N_W1;
    if (i < N_W2) { const int n = i >> 7, k = i & 127; w2t[i] = (__bf16)W2[k * EE + n]; return; }
    i -= N_W2;
    if (i < N_UQ) { uqA[i] = query[i]; uqB[i] = 0.f; }
}

// ---------------------------------------------------------------------------
// Fused embed gather-sum (bf16 table) + add_lm + MFMA MLP, 3 hops in one grid.
// hop 0: logits0 computed in-register (Y . query), m0 NEVER stored.
// hops 1,2: Y stored bf16 to mout[hop-1].
// 3072 blocks x 32 rows, 256 threads = 4 waves.
// ---------------------------------------------------------------------------
__global__ __launch_bounds__(256)
void embed_mlp_mfma(const int* __restrict__ story,
                    const int* __restrict__ kb_len,
                    const int* __restrict__ conv_len,
                    const __bf16* __restrict__ Cb,
                    const __bf16* __restrict__ dhb,
                    const __bf16* __restrict__ tfb,
                    const __bf16* __restrict__ w1t, const float* __restrict__ b1,
                    const __bf16* __restrict__ w2t, const float* __restrict__ b2,
                    const float* __restrict__ gp, const float* __restrict__ query,
                    __bf16* __restrict__ mout, float* __restrict__ lbuf0)
{
    __shared__ __bf16 Xs[32 * XS_STRIDE];   // 16,896 B
    __shared__ __bf16 Hs[32 * HS_STRIDE];   //  8,704 B
    __shared__ int    sidx[32 * SS];
    float* plog = (float*)Hs;               // [32][4], aliases Hs after GEMM2 reads

    const int bid  = blockIdx.x;
    const int hop  = bid >> 10;             // 1024 blocks per hop
    const int row0 = (bid & 1023) * 32;
    const int b    = row0 >> 11;
    const int tid  = threadIdx.x;

    const __bf16* Ck = Cb + (size_t)hop * VV * EE;

    for (int i = tid; i < 32 * SS; i += 256) sidx[i] = story[(size_t)row0 * SS + i];

    const int kb   = kb_len[b];
    const int cl   = conv_len[b];
    const int rgrp = tid >> 4;              // 0..15
    const int e8   = (tid & 15) * 8;
    const bf16x8 tf8 = *(const bf16x8*)&tfb[b * EE + e8];
    __syncthreads();

    // ---- gather: 2 passes x 16 rows; all loads issued before use (MLP) ----
    bf16x8 g[2][SS], dv[2];
    #pragma unroll
    for (int p = 0; p < 2; ++p) {
        const int r = p * 16 + rgrp;
        const int* si = &sidx[r * SS];
        #pragma unroll
        for (int s = 0; s < SS; ++s)
            g[p][s] = *(const bf16x8*)&Ck[(size_t)si[s] * EE + e8];
        const int j = ((row0 + r) & (MM - 1)) - kb;
        if (j >= 0 && j < cl) {
            dv[p] = *(const bf16x8*)&dhb[((size_t)b * LCC + j) * EE + e8];
        } else {
            bf16x8 z;
            #pragma unroll
            for (int q = 0; q < 8; ++q) z[q] = (__bf16)0.f;
            dv[p] = z;
        }
    }
    #pragma unroll
    for (int p = 0; p < 2; ++p) {
        const int r = p * 16 + rgrp;
        bf16x8 pk;
        #pragma unroll
        for (int q = 0; q < 8; ++q) {
            float s = (float)dv[p][q];
            #pragma unroll
            for (int s6 = 0; s6 < SS; ++s6) s += (float)g[p][s6][q];
            pk[q] = (__bf16)s;
        }
        *(bf16x8*)&Xs[r * XS_STRIDE + e8]      = pk;
        *(bf16x8*)&Xs[r * XS_STRIDE + EE + e8] = tf8;
    }
    __syncthreads();

    const int w       = tid >> 6;
    const int lane    = tid & 63;
    const int lr      = lane & 15;
    const int lk      = lane >> 4;
    const int colbase = w * 32;

    // ---- GEMM1: H = lrelu(X @ W1 + b1) ----
    f32x4 acc1[2][2];
    #pragma unroll
    for (int i = 0; i < 2; ++i)
        #pragma unroll
        for (int j = 0; j < 2; ++j) acc1[i][j] = (f32x4){0.f, 0.f, 0.f, 0.f};

    for (int ks = 0; ks < 8; ++ks) {
        bf16x8 a[2], bw[2];
        #pragma unroll
        for (int mt = 0; mt < 2; ++mt)
            a[mt] = *(const bf16x8*)&Xs[(mt * 16 + lr) * XS_STRIDE + ks * 32 + lk * 8];
        #pragma unroll
        for (int nt = 0; nt < 2; ++nt)
            bw[nt] = *(const bf16x8*)&w1t[(size_t)(colbase + nt * 16 + lr) * 256 + ks * 32 + lk * 8];
        #pragma unroll
        for (int mt = 0; mt < 2; ++mt)
            #pragma unroll
            for (int nt = 0; nt < 2; ++nt)
                acc1[mt][nt] = __builtin_amdgcn_mfma_f32_16x16x32_bf16(a[mt], bw[nt], acc1[mt][nt], 0, 0, 0);
    }
    {
        const float b1v[2] = { b1[colbase + lr], b1[colbase + 16 + lr] };
        #pragma unroll
        for (int mt = 0; mt < 2; ++mt)
            #pragma unroll
            for (int nt = 0; nt < 2; ++nt)
                #pragma unroll
                for (int reg = 0; reg < 4; ++reg) {
                    float h = acc1[mt][nt][reg] + b1v[nt];
                    h = (h > 0.f) ? h : 0.1f * h;
                    Hs[(mt * 16 + lk * 4 + reg) * HS_STRIDE + colbase + nt * 16 + lr] = (__bf16)h;
                }
    }
    __syncthreads();

    // ---- GEMM2: Y = H @ W2 + b2 ----
    f32x4 acc2[2][2];
    #pragma unroll
    for (int i = 0; i < 2; ++i)
        #pragma unroll
        for (int j = 0; j < 2; ++j) acc2[i][j] = (f32x4){0.f, 0.f, 0.f, 0.f};

    for (int ks = 0; ks < 4; ++ks) {
        bf16x8 a[2], bw[2];
        #pragma unroll
        for (int mt = 0; mt < 2; ++mt)
            a[mt] = *(const bf16x8*)&Hs[(mt * 16 + lr) * HS_STRIDE + ks * 32 + lk * 8];
        #pragma unroll
        for (int nt = 0; nt < 2; ++nt)
            bw[nt] = *(const bf16x8*)&w2t[(size_t)(colbase + nt * 16 + lr) * 128 + ks * 32 + lk * 8];
        #pragma unroll
        for (int mt = 0; mt < 2; ++mt)
            #pragma unroll
            for (int nt = 0; nt < 2; ++nt)
                acc2[mt][nt] = __builtin_amdgcn_mfma_f32_16x16x32_bf16(a[mt], bw[nt], acc2[mt][nt], 0, 0, 0);
    }

    const float b2v[2] = { b2[colbase + lr], b2[colbase + 16 + lr] };

    if (hop == 0) {
        // ---- fused logits0: l[row] = gp * sum_col Y[row][col]*query[b][col] ----
        const float qv0 = query[b * EE + colbase + lr];
        const float qv1 = query[b * EE + colbase + 16 + lr];
        __syncthreads();    // all GEMM2 Hs reads done; reuse Hs as plog
        #pragma unroll
        for (int mt = 0; mt < 2; ++mt)
            #pragma unroll
            for (int reg = 0; reg < 4; ++reg) {
                float p = (acc2[mt][0][reg] + b2v[0]) * qv0
                        + (acc2[mt][1][reg] + b2v[1]) * qv1;
                p += __shfl_xor(p, 1, 64);
                p += __shfl_xor(p, 2, 64);
                p += __shfl_xor(p, 4, 64);
                p += __shfl_xor(p, 8, 64);
                if (lr == 0) plog[(mt * 16 + lk * 4 + reg) * 4 + w] = p;
            }
        __syncthreads();
        if (tid < 32) {
            const float l = plog[tid * 4] + plog[tid * 4 + 1] + plog[tid * 4 + 2] + plog[tid * 4 + 3];
            lbuf0[row0 + tid] = l * gp[row0 + tid];
        }
    } else {
        __bf16* out = mout + (size_t)(hop - 1) * 32768 * EE;
        #pragma unroll
        for (int mt = 0; mt < 2; ++mt)
            #pragma unroll
            for (int nt = 0; nt < 2; ++nt)
                #pragma unroll
                for (int reg = 0; reg < 4; ++reg) {
                    const int rg_ = row0 + mt * 16 + lk * 4 + reg;
                    out[(size_t)rg_ * EE + colbase + nt * 16 + lr] =
                        (__bf16)(acc2[mt][nt][reg] + b2v[nt]);
                }
    }
}

// ---------------------------------------------------------------------------
// update: inline softmax of lbuf[b,:] (recomputed per block), then
// uq[b,:] += sum over 64 rows of gp*soft * mk[row,:].  512 blocks x 256.
// ---------------------------------------------------------------------------
__global__ __launch_bounds__(256)
void update_kernel(const __bf16* __restrict__ mk, const float* __restrict__ gp,
                   const float* __restrict__ lbuf, float* __restrict__ uq)
{
    __shared__ float redm[4], reds[4];
    __shared__ float wls[64];
    __shared__ float part[4][128];

    const int b      = blockIdx.x >> 5;
    const int rloc0  = (blockIdx.x & 31) * 64;
    const int tid    = threadIdx.x;
    const int lane   = tid & 63;
    const int w      = tid >> 6;
    const float* lb  = lbuf + (size_t)b * MM;

    // softmax stats over all 2048 logits of this b
    float v[8];
    float mx = -1e30f;
    #pragma unroll
    for (int i = 0; i < 8; ++i) { v[i] = lb[i * 256 + tid]; mx = fmaxf(mx, v[i]); }
    #pragma unroll
    for (int off = 32; off > 0; off >>= 1) mx = fmaxf(mx, __shfl_xor(mx, off, 64));
    if (lane == 0) redm[w] = mx;
    __syncthreads();
    mx = fmaxf(fmaxf(redm[0], redm[1]), fmaxf(redm[2], redm[3]));
    float sum = 0.f;
    #pragma unroll
    for (int i = 0; i < 8; ++i) sum += __expf(v[i] - mx);
    #pragma unroll
    for (int off = 32; off > 0; off >>= 1) sum += __shfl_xor(sum, off, 64);
    if (lane == 0) reds[w] = sum;
    __syncthreads();
    const float inv = 1.f / (reds[0] + reds[1] + reds[2] + reds[3]);

    if (tid < 64)
        wls[tid] = gp[(size_t)b * MM + rloc0 + tid] * __expf(lb[rloc0 + tid] - mx) * inv;
    __syncthreads();

    // accumulate: 4 passes x 16 rows; lane covers 8 cols
    const int rgrp = tid >> 4;
    const int e8   = (tid & 15) * 8;
    float acc[8];
    #pragma unroll
    for (int q = 0; q < 8; ++q) acc[q] = 0.f;
    #pragma unroll
    for (int p = 0; p < 4; ++p) {
        const int rl  = p * 16 + rgrp;
        const float wg = wls[rl];
        const bf16x8 vv = *(const bf16x8*)&mk[((size_t)b * MM + rloc0 + rl) * EE + e8];
        #pragma unroll
        for (int q = 0; q < 8; ++q) acc[q] += wg * (float)vv[q];
    }
    #pragma unroll
    for (int q = 0; q < 8; ++q) {
        acc[q] += __shfl_xor(acc[q], 16, 64);
        acc[q] += __shfl_xor(acc[q], 32, 64);
    }
    if (lane < 16) {
        #pragma unroll
        for (int q = 0; q < 8; ++q) part[w][e8 + q] = acc[q];
    }
    __syncthreads();
    if (tid < 128) {
        const float s = part[0][tid] + part[1][tid] + part[2][tid] + part[3][tid];
        atomicAdd(&uq[b * EE + tid], s);
    }
}

// ---------------------------------------------------------------------------
// logits[row] = gp[row] * dot(mk[row,:], uqa[b]+uqb[b]).  512 blocks x 64 rows.
// ---------------------------------------------------------------------------
__global__ __launch_bounds__(256)
void logits_kernel(const __bf16* __restrict__ mk, const float* __restrict__ gp,
                   const float* __restrict__ uqa, const float* __restrict__ uqb,
                   float* __restrict__ out)
{
    __shared__ float uqs[128];
    const int row0 = blockIdx.x * 64;
    const int b    = row0 >> 11;
    const int tid  = threadIdx.x;
    if (tid < 128) uqs[tid] = uqa[b * EE + tid] + (uqb ? uqb[b * EE + tid] : 0.f);
    __syncthreads();
    const int w = tid >> 6, lane = tid & 63;
    const int g = lane >> 4, l16 = lane & 15;
    float u[8];
    #pragma unroll
    for (int j = 0; j < 8; ++j) u[j] = uqs[l16 * 8 + j];
    #pragma unroll
    for (int it = 0; it < 4; ++it) {
        const int row = row0 + it * 16 + w * 4 + g;
        const bf16x8 v = *(const bf16x8*)&mk[(size_t)row * EE + l16 * 8];
        float p = 0.f;
        #pragma unroll
        for (int j = 0; j < 8; ++j) p += (float)v[j] * u[j];
        p += __shfl_xor(p, 1, 64);
        p += __shfl_xor(p, 2, 64);
        p += __shfl_xor(p, 4, 64);
        p += __shfl_xor(p, 8, 64);
        if (l16 == 0) out[row] = p * gp[row];
    }
}

// ---------------------------------------------------------------------------
// final softmax: block per b, writes prob_soft only.
// ---------------------------------------------------------------------------
__global__ __launch_bounds__(256)
void softmax_final(const float* __restrict__ logits, float* __restrict__ soft)
{
    __shared__ float redm[4], reds[4];
    const int b = blockIdx.x, tid = threadIdx.x;
    const int lane = tid & 63, w = tid >> 6;
    const float* lb = logits + (size_t)b * MM;
    float v[8];
    float mx = -1e30f;
    #pragma unroll
    for (int i = 0; i < 8; ++i) { v[i] = lb[i * 256 + tid]; mx = fmaxf(mx, v[i]); }
    #pragma unroll
    for (int off = 32; off > 0; off >>= 1) mx = fmaxf(mx, __shfl_xor(mx, off, 64));
    if (lane == 0) redm[w] = mx;
    __syncthreads();
    mx = fmaxf(fmaxf(redm[0], redm[1]), fmaxf(redm[2], redm[3]));
    float sum = 0.f;
    #pragma unroll
    for (int i = 0; i < 8; ++i) { v[i] = __expf(v[i] - mx); sum += v[i]; }
    #pragma unroll
    for (int off = 32; off > 0; off >>= 1) sum += __shfl_xor(sum, off, 64);
    if (lane == 0) reds[w] = sum;
    __syncthreads();
    const float inv = 1.f / (reds[0] + reds[1] + reds[2] + reds[3]);
    #pragma unroll
    for (int i = 0; i < 8; ++i) soft[(size_t)b * MM + i * 256 + tid] = v[i] * inv;
}

// ---------------------------------------------------------------------------
extern "C" void kernel_launch(void* const* d_in, const int* in_sizes, int n_in,
                              void* d_out, int out_size, void* d_ws, size_t ws_size,
                              hipStream_t stream) {
    const int*   story    = (const int*)d_in[0];
    const int*   kb_len   = (const int*)d_in[1];
    const int*   conv_len = (const int*)d_in[2];
    // d_in[3] = hidden (dead w.r.t. outputs)
    const float* dh       = (const float*)d_in[4];
    const float* tf       = (const float*)d_in[5];
    const float* query    = (const float*)d_in[6];
    const float* gp       = (const float*)d_in[7];
    const float* C        = (const float*)d_in[8];
    const float* wA1      = (const float*)d_in[9];
    const float* bA1      = (const float*)d_in[10];
    const float* wA2      = (const float*)d_in[11];
    const float* bA2      = (const float*)d_in[12];
    // wC1/bC1/wC2/bC2, wf/bf: dead w.r.t. outputs

    char* ws = (char*)d_ws;
    const size_t M_ELEMS = (size_t)32768 * EE;
    size_t off = 0;
    __bf16* m   = (__bf16*)(ws + off); off += 2 * M_ELEMS * sizeof(__bf16);        // m1, m2
    __bf16* Cb  = (__bf16*)(ws + off); off += (size_t)3 * VV * EE * sizeof(__bf16);
    __bf16* dhb = (__bf16*)(ws + off); off += (size_t)BB * LCC * EE * sizeof(__bf16);
    __bf16* tfb = (__bf16*)(ws + off); off += (size_t)BB * EE * sizeof(__bf16);
    __bf16* w1t = (__bf16*)(ws + off); off += 256 * 128 * sizeof(__bf16);
    __bf16* w2t = (__bf16*)(ws + off); off += 128 * 128 * sizeof(__bf16);
    float* lbuf = (float*)(ws + off);  off += (size_t)BB * MM * sizeof(float);
    float* uqA  = (float*)(ws + off);  off += (size_t)BB * EE * sizeof(float);
    float* uqB  = (float*)(ws + off);  off += (size_t)BB * EE * sizeof(float);

    float* out_soft   = (float*)d_out;
    float* out_logits = out_soft + (size_t)BB * MM;

    megaprep<<<N_PREP / 256, 256, 0, stream>>>(C, dh, tf, wA1, wA2, query,
                                               Cb, dhb, tfb, w1t, w2t, uqA, uqB);
    embed_mlp_mfma<<<3072, 256, 0, stream>>>(story, kb_len, conv_len, Cb, dhb, tfb,
                                             w1t, bA1, w2t, bA2, gp, query, m, lbuf);
    // hop1: uqA = query + m1^T(gp*soft0);  logits1 -> lbuf
    update_kernel<<<512, 256, 0, stream>>>(m, gp, lbuf, uqA);
    logits_kernel<<<512, 256, 0, stream>>>(m, gp, uqA, nullptr, lbuf);
    // hop2: uqB = m2^T(gp*soft1);  logits2 with uqA+uqB -> out_logits
    update_kernel<<<512, 256, 0, stream>>>(m + M_ELEMS, gp, lbuf, uqB);
    logits_kernel<<<512, 256, 0, stream>>>(m + M_ELEMS, gp, uqA, uqB, out_logits);
    softmax_final<<<BB, 256, 0, stream>>>(out_logits, out_soft);
}